// Round 13
// baseline (110.519 us; speedup 1.0000x reference)
//
#include <hip/hip_runtime.h>
#include <hip/hip_bf16.h>
#include <cstddef>

#define NE 65536
#define ND 256
#define NP 8
#define SB 32                 // edges per repack sub-block
#define NSB (NE / SB)         // 2048 sub-blocks
#define TR 32                 // rows per main tile
#define MAXT 2056             // max tiles: 2048 + 8

typedef short bf16x8 __attribute__((ext_vector_type(8)));
typedef float f32x4  __attribute__((ext_vector_type(4)));
typedef const __attribute__((address_space(1))) unsigned int* gas_t;
typedef __attribute__((address_space(3))) unsigned int* las_t;

__device__ __forceinline__ unsigned short f2bf(float f) {
  unsigned int u = __float_as_uint(f);
  u += 0x7FFFu + ((u >> 16) & 1u);   // round-to-nearest-even
  return (unsigned short)(u >> 16);
}
__device__ __forceinline__ float bf2f(unsigned short h) {
  return __uint_as_float(((unsigned int)h) << 16);
}
__device__ __forceinline__ int load_idx(const void* idxraw, int is32, int e) {
  return is32 ? ((const int*)idxraw)[e] : (int)((const long long*)idxraw)[e];
}
// idx dtype sniff: odd 32-bit words all-zero <=> int64 (values < 8)
__device__ __forceinline__ int sniff_is32(const void* idxraw, int* lflag) {
  int tid = threadIdx.x;
  if (tid == 0) *lflag = 0;
  __syncthreads();
  const unsigned int* w = (const unsigned int*)idxraw;
  unsigned int val = w[(((int)blockIdx.x & 63) * 256 + (tid & 255)) * 2 + 1];
  if (__any(val != 0) && (tid & 63) == 0) atomicOr(lflag, 1);
  __syncthreads();
  return *lflag;
}

// ---- k_pre0: WbT frag (b<32), v (b<40), ballot histogram (b>=40) ----
__global__ __launch_bounds__(256) void k_pre0(const float* __restrict__ Wbil,
                                              const float* __restrict__ blr,
                                              const void* __restrict__ idxraw,
                                              unsigned short* __restrict__ WbT,
                                              float* __restrict__ v,
                                              int* __restrict__ counts) {
  int b = blockIdx.x, t = threadIdx.x;
  if (b < 32) {
    int s = b * 256 + t;
    int kt = s >> 10, c = (s >> 6) & 15, l = s & 63;
    int col = c * 16 + (l & 15);
    int k0 = kt * 32 + (l >> 4) * 8;
    union { uint4 u; unsigned short h[8]; } uu;
#pragma unroll
    for (int j = 0; j < 8; ++j)
      uu.h[j] = f2bf(Wbil[(k0 + j) * ND + col]);
    *(uint4*)(WbT + (size_t)s * 8) = uu.u;
  } else if (b < 40) {
    int p = b - 32;
    float s = 0.f;
    for (int k = 0; k < ND; ++k)
      s = fmaf(blr[p * ND + k], Wbil[k * ND + t], s);
    v[p * ND + t] = s;
  } else {
    __shared__ int lflag;
    int is32 = sniff_is32(idxraw, &lflag);
    int hb = b - 40;                       // 0..255, each covers 256 edges
    int w = t >> 6, l = t & 63;
    int e = hb * 256 + w * 64 + l;
    int p = load_idx(idxraw, is32, e);
    int sb0 = hb * 8 + w * 2;              // two 32-edge sub-blocks per wave
#pragma unroll
    for (int q = 0; q < NP; ++q) {
      unsigned long long m = __ballot(p == q);
      if (l == q)      counts[q * NSB + sb0]     = __popcll(m & 0xFFFFFFFFull);
      if (l == 32 + q) counts[q * NSB + sb0 + 1] = __popcll(m >> 32);
    }
  }
}

// ---- k_scan: totals, CSR offsets, tile prefix, per-sub-block bases ----
__global__ __launch_bounds__(256) void k_scan(const int* __restrict__ counts,
                                              int* __restrict__ hdr,
                                              int* __restrict__ bases) {
  __shared__ int part[NP][32], cpre[NP][32], cnt[NP], shoff[NP];
  int t = threadIdx.x;
  int q = t >> 5, i = t & 31;
  int s = 0;
  for (int j = 0; j < 64; ++j) s += counts[q * NSB + i * 64 + j];
  part[q][i] = s;
  __syncthreads();
  if (t < NP) {
    int run = 0;
    for (int k = 0; k < 32; ++k) { cpre[t][k] = run; run += part[t][k]; }
    cnt[t] = run;
  }
  __syncthreads();
  if (t == 0) {
    int o = 0, tt = 0;
    for (int p = 0; p < NP; ++p) {
      shoff[p] = o; hdr[p] = o; hdr[9 + p] = tt;
      o += cnt[p];
      tt += (cnt[p] + TR - 1) / TR;
    }
    hdr[NP] = o; hdr[9 + NP] = tt;
  }
  __syncthreads();
  int run = shoff[q] + cpre[q][i];
  for (int j = 0; j < 64; ++j) {
    int sb = i * 64 + j;
    bases[q * NSB + sb] = run;
    run += counts[q * NSB + sb];
  }
}

// ---- k_cpre: C_p = W_lr[p]^T @ W_bil (bf16 MFMA), B-frag layout ----
__global__ __launch_bounds__(256) void k_cpre(const float* __restrict__ Wlr,
                                              const unsigned short* __restrict__ WbT,
                                              unsigned short* __restrict__ Cst) {
  __shared__ unsigned short aF[2048 * 8];
  int blk = blockIdx.x;
  int p = blk >> 2;
  int i0 = (blk & 3) * 64;
  int tid = threadIdx.x;
  const float* Wp = Wlr + (size_t)p * ND * ND;
#pragma unroll
  for (int it = 0; it < 8; ++it) {
    int s = tid + it * 256;
    int kt = s >> 8, r = (s >> 6) & 3, l = s & 63;
    int i = r * 16 + (l & 15);
    int k0 = kt * 32 + (l >> 4) * 8;
    union { uint4 u; unsigned short h[8]; } uu;
#pragma unroll
    for (int j = 0; j < 8; ++j)
      uu.h[j] = f2bf(Wp[(size_t)(k0 + j) * ND + i0 + i]);
    *(uint4*)(aF + (size_t)s * 8) = uu.u;
  }
  __syncthreads();
  int w = tid >> 6, l = tid & 63;
  f32x4 zero = {0.f, 0.f, 0.f, 0.f};
  f32x4 acc[16];
#pragma unroll
  for (int c = 0; c < 16; ++c) acc[c] = zero;
  for (int kt = 0; kt < 8; ++kt) {
    bf16x8 a = *(const bf16x8*)(aF + (size_t)((kt * 4 + w) * 64 + l) * 8);
#pragma unroll
    for (int c = 0; c < 16; ++c) {
      bf16x8 bb = *(const bf16x8*)(WbT + (size_t)((kt * 16 + c) * 64 + l) * 8);
      acc[c] = __builtin_amdgcn_mfma_f32_16x16x32_bf16(a, bb, acc[c], 0, 0, 0);
    }
  }
  unsigned short* Cp = Cst + (size_t)p * ND * ND;
#pragma unroll
  for (int c = 0; c < 16; ++c) {
#pragma unroll
    for (int q = 0; q < 4; ++q) {
      int i = i0 + w * 16 + ((l >> 4) * 4) + q;
      int j = c * 16 + (l & 15);
      int pos = ((i >> 5) * 16 + (j >> 4)) * 512 + (((i >> 3) & 3) * 16 + (j & 15)) * 8 + (i & 7);
      Cp[pos] = f2bf(acc[c][q]);
    }
  }
}

// ---- k_repack: sequential-read local-sort bf16 repack (no atomics) ----
// 2048 blocks x 32 consecutive edges. Reads: contiguous 64KB/block (async
// global_load_lds). Writes: per-expert contiguous runs of 512B bf16 rows
// (line-aligned, no RMW) into sorted zsP/zdP; also writes perm.
__global__ __launch_bounds__(256) void k_repack(const void* __restrict__ idxraw,
                                                const float* __restrict__ zsrc,
                                                const float* __restrict__ zdst,
                                                const int* __restrict__ bases,
                                                int* __restrict__ perm,
                                                unsigned short* __restrict__ zsP,
                                                unsigned short* __restrict__ zdP) {
  __shared__ float zsL[SB * 256];        // 32 KiB
  __shared__ float zdL[SB * 256];        // 32 KiB
  __shared__ int lsrcS[SB], garowS[SB];
  __shared__ int lflag;
  int tid = threadIdx.x;
  int b = blockIdx.x;
  int is32 = sniff_is32(idxraw, &lflag);
  int w = tid >> 6, l = tid & 63;
  int base = b * SB;
  // ---- async staging: 64 rows (32 zs + 32 zd); wave w rows [w*16, w*16+16)
#pragma unroll
  for (int i = 0; i < 16; ++i) {
    int r = w * 16 + i;
    const float* g = (r < SB) ? (zsrc + (size_t)(base + r) * ND + l * 4)
                              : (zdst + (size_t)(base + r - SB) * ND + l * 4);
    float* ldsb = (r < SB) ? (zsL + r * 256) : (zdL + (r - SB) * 256);
    __builtin_amdgcn_global_load_lds((gas_t)(const void*)g,
                                     (las_t)(void*)ldsb, 16, 0, 0);
  }
  // ---- sort tables (wave 0, under load latency) ----
  if (w == 0) {
    int p = (l < SB) ? load_idx(idxraw, is32, base + l) : 999;
    unsigned long long lt = (l == 63) ? ~0ull >> 1 : ((1ull << l) - 1ull);
    int loffq = 0, slot = 0, rank = 0, gq = 0;
#pragma unroll
    for (int q = 0; q < NP; ++q) {
      unsigned long long m = __ballot(p == q);
      if (p == q) { rank = __popcll(m & lt); slot = loffq + rank; gq = q; }
      loffq += __popcll(m);
    }
    if (l < SB) {
      lsrcS[slot] = l;
      int g = bases[gq * NSB + b] + rank;
      garowS[slot] = g;
      perm[g] = base + l;
    }
  }
  __syncthreads();   // drains vmcnt (tiles resident) + table visibility
  // ---- flush: 8 half-waves x 8 output rows (rows 0..31 zs, 32..63 zd) ----
  int hw = tid >> 5, ln = tid & 31;
#pragma unroll
  for (int i = 0; i < 8; ++i) {
    int orow = hw * 8 + i;
    int s = orow & (SB - 1);
    int n = lsrcS[s];
    size_t g = (size_t)garowS[s];
    const float* srcRow = (orow < SB) ? (zsL + n * 256) : (zdL + n * 256);
    unsigned short* dst = ((orow < SB) ? zsP : zdP) + g * 256 + ln * 8;
    float4 a0 = *(const float4*)(srcRow + ln * 8);
    float4 a1 = *(const float4*)(srcRow + ln * 8 + 4);
    union { uint4 u; unsigned short h[8]; } o;
    o.h[0] = f2bf(a0.x); o.h[1] = f2bf(a0.y); o.h[2] = f2bf(a0.z); o.h[3] = f2bf(a0.w);
    o.h[4] = f2bf(a1.x); o.h[5] = f2bf(a1.y); o.h[6] = f2bf(a1.z); o.h[7] = f2bf(a1.w);
    *(uint4*)dst = o.u;
  }
}

// ---- k_perm (fallback, small ws): perm only, ballot-based, no atomics ----
__global__ __launch_bounds__(64) void k_perm(const void* __restrict__ idxraw,
                                             const int* __restrict__ bases,
                                             int* __restrict__ perm) {
  __shared__ int lflag;
  int l = threadIdx.x;
  int b = blockIdx.x;
  int is32 = sniff_is32(idxraw, &lflag);
  int base = b * SB;
  int p = (l < SB) ? load_idx(idxraw, is32, base + l) : 999;
  unsigned long long lt = (l == 63) ? ~0ull >> 1 : ((1ull << l) - 1ull);
  int loffq = 0, rank = 0, gq = -1;
#pragma unroll
  for (int q = 0; q < NP; ++q) {
    unsigned long long m = __ballot(p == q);
    if (p == q) { rank = __popcll(m & lt); gq = q; }
    loffq += __popcll(m);
  }
  if (l < SB) perm[bases[gq * NSB + b] + rank] = base + l;
}

// ---- k_main_s: sorted bf16 tiles, FULLY SEQUENTIAL reads (32KB/tile) ----
__global__ __launch_bounds__(512, 8) void k_main_s(const unsigned short* __restrict__ zsP,
                                                   const unsigned short* __restrict__ zdP,
                                                   const int* __restrict__ perm,
                                                   const int* __restrict__ hdr,
                                                   const unsigned short* __restrict__ Cst,
                                                   const float* __restrict__ v,
                                                   const float* __restrict__ bbil,
                                                   float* __restrict__ out) {
  __shared__ unsigned short zs[8192];    // 16 KiB: A-frag layout, granule-XOR
  __shared__ unsigned short zd[8192];    // 16 KiB: row-major 512B/row, XOR
  __shared__ float red[8][TR];
  __shared__ int eids[TR];
  __shared__ int shdr[18];
  int tid = threadIdx.x;
  if (tid < 18) shdr[tid] = hdr[tid];
  __syncthreads();
  int bid = blockIdx.x;
  if (bid >= shdr[9 + NP]) return;
  int p = 0;
  while (p < NP - 1 && bid >= shdr[9 + p + 1]) ++p;
  int t = bid - shdr[9 + p];
  int cnt = shdr[p + 1] - shdr[p];
  int ebase = shdr[p] + t * TR;
  int nrow = cnt - t * TR; if (nrow > TR) nrow = TR;
  if (tid < TR) eids[tid] = perm[ebase + (tid < nrow ? tid : nrow - 1)];
  int w = tid >> 6, l = tid & 63;
  // ---- staging: sequential bf16 rows; wave w rows w*4..w*4+3 ----
  int kt0 = l >> 3, q0 = (l >> 1) & 3, par0 = l & 1;
#pragma unroll
  for (int i = 0; i < 4; ++i) {
    int row = w * 4 + i;
    int grow = ebase + row; if (grow > NE - 1) grow = NE - 1;
    unsigned long long us = *(const unsigned long long*)(zsP + (size_t)grow * 256 + l * 4);
    unsigned long long ud = *(const unsigned long long*)(zdP + (size_t)grow * 256 + l * 4);
    unsigned g = (unsigned)((kt0 * 2 + (row >> 4)) * 64 + (row & 15) + 16 * q0);
    g ^= ((g >> 6) & 7u) << 1;
    *(unsigned long long*)((char*)zs + g * 16 + par0 * 8) = us;
    *(unsigned long long*)((char*)zd + ((unsigned)(row * 512 + l * 8) ^ (((unsigned)row & 7u) << 5))) = ud;
  }
  __syncthreads();
  // ---- GEMM: wave w covers col-tiles {2w, 2w+1}; B from L2 ----
  const unsigned short* Cp = Cst + (size_t)p * ND * ND;
  f32x4 zero = {0.f, 0.f, 0.f, 0.f};
  f32x4 acc[2][2];
#pragma unroll
  for (int sr = 0; sr < 2; ++sr)
#pragma unroll
    for (int cl = 0; cl < 2; ++cl) acc[sr][cl] = zero;
  int hh = l >> 4, rr = l & 15;
#pragma unroll
  for (int kt = 0; kt < 8; ++kt) {
    bf16x8 a[2];
#pragma unroll
    for (int sr = 0; sr < 2; ++sr) {
      unsigned g = (unsigned)((kt * 2 + sr) * 64 + l);
      g ^= ((g >> 6) & 7u) << 1;
      a[sr] = *(const bf16x8*)((const char*)zs + g * 16);
    }
#pragma unroll
    for (int cl = 0; cl < 2; ++cl) {
      bf16x8 bb = *(const bf16x8*)(Cp + (size_t)((kt * 16 + (w * 2 + cl)) * 64 + l) * 8);
#pragma unroll
      for (int sr = 0; sr < 2; ++sr)
        acc[sr][cl] = __builtin_amdgcn_mfma_f32_16x16x32_bf16(a[sr], bb, acc[sr][cl], 0, 0, 0);
    }
  }
  // ---- fused epilogue ----
  float vloc[2];
#pragma unroll
  for (int cl = 0; cl < 2; ++cl)
    vloc[cl] = v[p * ND + (w * 2 + cl) * 16 + rr];
#pragma unroll
  for (int sr = 0; sr < 2; ++sr) {
#pragma unroll
    for (int q = 0; q < 4; ++q) {
      int row = sr * 16 + hh * 4 + q;
      unsigned swz = ((unsigned)row & 7u) << 5;
      float sv = 0.f;
#pragma unroll
      for (int cl = 0; cl < 2; ++cl) {
        int col = (w * 2 + cl) * 16 + rr;
        unsigned byte = ((unsigned)(row * 512 + col * 2)) ^ swz;
        sv = fmaf(acc[sr][cl][q] + vloc[cl], bf2f(*(const unsigned short*)((const char*)zd + byte)), sv);
      }
      sv += __shfl_xor(sv, 1, 64);
      sv += __shfl_xor(sv, 2, 64);
      sv += __shfl_xor(sv, 4, 64);
      sv += __shfl_xor(sv, 8, 64);
      if (rr == 0) red[w][row] = sv;
    }
  }
  __syncthreads();
  if (tid < TR && tid < nrow) {
    float sc = bbil[0];
#pragma unroll
    for (int ww = 0; ww < 8; ++ww) sc += red[ww][tid];
    out[eids[tid]] = sc;
  }
}

// ---- k_main_g (fallback): R12 gather version (fp32 + cvt) ----
__global__ __launch_bounds__(512, 8) void k_main_g(const float* __restrict__ zsrc,
                                                   const float* __restrict__ zdst,
                                                   const int* __restrict__ perm,
                                                   const int* __restrict__ hdr,
                                                   const unsigned short* __restrict__ Cst,
                                                   const float* __restrict__ v,
                                                   const float* __restrict__ bbil,
                                                   float* __restrict__ out) {
  __shared__ unsigned short zs[8192];
  __shared__ unsigned short zd[8192];
  __shared__ float red[8][TR];
  __shared__ int eids[TR];
  __shared__ int shdr[18];
  int tid = threadIdx.x;
  if (tid < 18) shdr[tid] = hdr[tid];
  __syncthreads();
  int bid = blockIdx.x;
  if (bid >= shdr[9 + NP]) return;
  int p = 0;
  while (p < NP - 1 && bid >= shdr[9 + p + 1]) ++p;
  int t = bid - shdr[9 + p];
  int cnt = shdr[p + 1] - shdr[p];
  int ebase = shdr[p] + t * TR;
  int nrow = cnt - t * TR; if (nrow > TR) nrow = TR;
  if (tid < TR) eids[tid] = perm[ebase + (tid < nrow ? tid : nrow - 1)];
  __syncthreads();
  int w = tid >> 6, l = tid & 63;
  int kt0 = l >> 3, q0 = (l >> 1) & 3, par0 = l & 1;
#pragma unroll
  for (int i = 0; i < 4; ++i) {
    int row = w * 4 + i;
    int e = eids[row];
    float4 fs = *(const float4*)(zsrc + (size_t)e * ND + l * 4);
    float4 fd = *(const float4*)(zdst + (size_t)e * ND + l * 4);
    union { unsigned long long u; unsigned short h[4]; } us, ud;
    us.h[0] = f2bf(fs.x); us.h[1] = f2bf(fs.y); us.h[2] = f2bf(fs.z); us.h[3] = f2bf(fs.w);
    ud.h[0] = f2bf(fd.x); ud.h[1] = f2bf(fd.y); ud.h[2] = f2bf(fd.z); ud.h[3] = f2bf(fd.w);
    unsigned g = (unsigned)((kt0 * 2 + (row >> 4)) * 64 + (row & 15) + 16 * q0);
    g ^= ((g >> 6) & 7u) << 1;
    *(unsigned long long*)((char*)zs + g * 16 + par0 * 8) = us.u;
    *(unsigned long long*)((char*)zd + ((unsigned)(row * 512 + l * 8) ^ (((unsigned)row & 7u) << 5))) = ud.u;
  }
  __syncthreads();
  const unsigned short* Cp = Cst + (size_t)p * ND * ND;
  f32x4 zero = {0.f, 0.f, 0.f, 0.f};
  f32x4 acc[2][2];
#pragma unroll
  for (int sr = 0; sr < 2; ++sr)
#pragma unroll
    for (int cl = 0; cl < 2; ++cl) acc[sr][cl] = zero;
  int hh = l >> 4, rr = l & 15;
#pragma unroll
  for (int kt = 0; kt < 8; ++kt) {
    bf16x8 a[2];
#pragma unroll
    for (int sr = 0; sr < 2; ++sr) {
      unsigned g = (unsigned)((kt * 2 + sr) * 64 + l);
      g ^= ((g >> 6) & 7u) << 1;
      a[sr] = *(const bf16x8*)((const char*)zs + g * 16);
    }
#pragma unroll
    for (int cl = 0; cl < 2; ++cl) {
      bf16x8 bb = *(const bf16x8*)(Cp + (size_t)((kt * 16 + (w * 2 + cl)) * 64 + l) * 8);
#pragma unroll
      for (int sr = 0; sr < 2; ++sr)
        acc[sr][cl] = __builtin_amdgcn_mfma_f32_16x16x32_bf16(a[sr], bb, acc[sr][cl], 0, 0, 0);
    }
  }
  float vloc[2];
#pragma unroll
  for (int cl = 0; cl < 2; ++cl)
    vloc[cl] = v[p * ND + (w * 2 + cl) * 16 + rr];
#pragma unroll
  for (int sr = 0; sr < 2; ++sr) {
#pragma unroll
    for (int q = 0; q < 4; ++q) {
      int row = sr * 16 + hh * 4 + q;
      unsigned swz = ((unsigned)row & 7u) << 5;
      float sv = 0.f;
#pragma unroll
      for (int cl = 0; cl < 2; ++cl) {
        int col = (w * 2 + cl) * 16 + rr;
        unsigned byte = ((unsigned)(row * 512 + col * 2)) ^ swz;
        sv = fmaf(acc[sr][cl][q] + vloc[cl], bf2f(*(const unsigned short*)((const char*)zd + byte)), sv);
      }
      sv += __shfl_xor(sv, 1, 64);
      sv += __shfl_xor(sv, 2, 64);
      sv += __shfl_xor(sv, 4, 64);
      sv += __shfl_xor(sv, 8, 64);
      if (rr == 0) red[w][row] = sv;
    }
  }
  __syncthreads();
  if (tid < TR && tid < nrow) {
    float sc = bbil[0];
#pragma unroll
    for (int ww = 0; ww < 8; ++ww) sc += red[ww][tid];
    out[eids[tid]] = sc;
  }
}

extern "C" void kernel_launch(void* const* d_in, const int* in_sizes, int n_in,
                              void* d_out, int out_size, void* d_ws, size_t ws_size,
                              hipStream_t stream) {
  // setup_inputs() dict order: z_src, z_dst, W_lr, b_lr, W_bil, b_bil, lr_pair_idx
  const float* zsrc = (const float*)d_in[0];
  const float* zdst = (const float*)d_in[1];
  const float* Wlr  = (const float*)d_in[2];
  const float* blr  = (const float*)d_in[3];
  const float* Wbil = (const float*)d_in[4];
  const float* bbil = (const float*)d_in[5];
  const void*  idx  = (const void*)d_in[6];
  float* out = (float*)d_out;

  char* ws = (char*)d_ws;
  int* hdr    = (int*)ws;                                  // 72 B
  int* counts = (int*)(ws + 4096);                         // 64 KiB [q][sb]
  int* bases  = (int*)(ws + 73728);                        // 64 KiB [q][sb]
  unsigned short* WbT = (unsigned short*)(ws + 139264);    // 128 KiB
  float* v            = (float*)(ws + 270336);             // 8 KiB
  unsigned short* Cst = (unsigned short*)(ws + 278528);    // 1 MiB
  int* perm           = (int*)(ws + 1327104);              // 256 KiB
  unsigned short* zsP = (unsigned short*)(ws + 2097152);            // 32 MiB
  unsigned short* zdP = (unsigned short*)(ws + 2097152 + 33554432); // 32 MiB
  size_t need = 2097152 + 2ull * 33554432;                 // 69206016 B

  k_pre0<<<296, 256, 0, stream>>>(Wbil, blr, idx, WbT, v, counts);
  k_scan<<<1, 256, 0, stream>>>(counts, hdr, bases);
  k_cpre<<<32, 256, 0, stream>>>(Wlr, WbT, Cst);
  if (ws_size >= need) {
    k_repack<<<NSB, 256, 0, stream>>>(idx, zsrc, zdst, bases, perm, zsP, zdP);
    k_main_s<<<MAXT, 512, 0, stream>>>(zsP, zdP, perm, hdr, Cst, v, bbil, out);
  } else {
    k_perm<<<NSB, 64, 0, stream>>>(idx, bases, perm);
    k_main_g<<<MAXT, 512, 0, stream>>>(zsrc, zdst, perm, hdr, Cst, v, bbil, out);
  }
}

// Round 14
// 87.480 us; speedup vs baseline: 1.2634x; 1.2634x over previous
//
#include <hip/hip_runtime.h>
#include <hip/hip_bf16.h>
#include <cstddef>

#define NE 65536
#define ND 256
#define NP 8
#define SB 32                 // edges per ballot window
#define NSB (NE / SB)         // 2048 windows
#define TR 32                 // rows per main tile

typedef short bf16x8 __attribute__((ext_vector_type(8)));
typedef float f32x4  __attribute__((ext_vector_type(4)));

__device__ __forceinline__ unsigned short f2bf(float f) {
  unsigned int u = __float_as_uint(f);
  u += 0x7FFFu + ((u >> 16) & 1u);   // round-to-nearest-even
  return (unsigned short)(u >> 16);
}
__device__ __forceinline__ float bf2f(unsigned short h) {
  return __uint_as_float(((unsigned int)h) << 16);
}
__device__ __forceinline__ int load_idx(const void* idxraw, int is32, int e) {
  return is32 ? ((const int*)idxraw)[e] : (int)((const long long*)idxraw)[e];
}
// idx dtype sniff: odd 32-bit words all-zero <=> int64 (values < 8)
__device__ __forceinline__ int sniff_is32(const void* idxraw, int* lflag) {
  int tid = threadIdx.x;
  if (tid == 0) *lflag = 0;
  __syncthreads();
  const unsigned int* w = (const unsigned int*)idxraw;
  unsigned int val = w[(((int)blockIdx.x & 63) * 256 + (tid & 255)) * 2 + 1];
  if (__any(val != 0) && (tid & 63) == 0) atomicOr(lflag, 1);
  __syncthreads();
  return *lflag;
}

// ---- k_pre0: WbT frag (b<32), v (b<40), ballot histogram (b>=40) ----
__global__ __launch_bounds__(256) void k_pre0(const float* __restrict__ Wbil,
                                              const float* __restrict__ blr,
                                              const void* __restrict__ idxraw,
                                              unsigned short* __restrict__ WbT,
                                              float* __restrict__ v,
                                              int* __restrict__ counts) {
  int b = blockIdx.x, t = threadIdx.x;
  if (b < 32) {
    int s = b * 256 + t;
    int kt = s >> 10, c = (s >> 6) & 15, l = s & 63;
    int col = c * 16 + (l & 15);
    int k0 = kt * 32 + (l >> 4) * 8;
    union { uint4 u; unsigned short h[8]; } uu;
#pragma unroll
    for (int j = 0; j < 8; ++j)
      uu.h[j] = f2bf(Wbil[(k0 + j) * ND + col]);
    *(uint4*)(WbT + (size_t)s * 8) = uu.u;
  } else if (b < 40) {
    int p = b - 32;
    float s = 0.f;
    for (int k = 0; k < ND; ++k)
      s = fmaf(blr[p * ND + k], Wbil[k * ND + t], s);
    v[p * ND + t] = s;
  } else {
    __shared__ int lflag;
    int is32 = sniff_is32(idxraw, &lflag);
    int hb = b - 40;                       // 0..255, each covers 256 edges
    int w = t >> 6, l = t & 63;
    int e = hb * 256 + w * 64 + l;
    int p = load_idx(idxraw, is32, e);
    int sb0 = hb * 8 + w * 2;              // two 32-edge windows per wave
#pragma unroll
    for (int q = 0; q < NP; ++q) {
      unsigned long long m = __ballot(p == q);
      if (l == q)      counts[q * NSB + sb0]     = __popcll(m & 0xFFFFFFFFull);
      if (l == 32 + q) counts[q * NSB + sb0 + 1] = __popcll(m >> 32);
    }
  }
}

// ---- k_scan: totals, CSR offsets, tile prefix, per-window bases ----
__global__ __launch_bounds__(256) void k_scan(const int* __restrict__ counts,
                                              int* __restrict__ hdr,
                                              int* __restrict__ bases) {
  __shared__ int part[NP][32], cpre[NP][32], cnt[NP], shoff[NP];
  int t = threadIdx.x;
  int q = t >> 5, i = t & 31;
  int s = 0;
  for (int j = 0; j < 64; ++j) s += counts[q * NSB + i * 64 + j];
  part[q][i] = s;
  __syncthreads();
  if (t < NP) {
    int run = 0;
    for (int k = 0; k < 32; ++k) { cpre[t][k] = run; run += part[t][k]; }
    cnt[t] = run;
  }
  __syncthreads();
  if (t == 0) {
    int o = 0, tt = 0;
    for (int p = 0; p < NP; ++p) {
      shoff[p] = o; hdr[p] = o; hdr[9 + p] = tt;
      o += cnt[p];
      tt += (cnt[p] + TR - 1) / TR;
    }
    hdr[NP] = o; hdr[9 + NP] = tt;
  }
  __syncthreads();
  int run = shoff[q] + cpre[q][i];
  for (int j = 0; j < 64; ++j) {
    int sb = i * 64 + j;
    bases[q * NSB + sb] = run;
    run += counts[q * NSB + sb];
  }
}

// ---- k_cpre: C_p = W_lr[p]^T @ W_bil (bf16 MFMA), B-frag layout ----
__global__ __launch_bounds__(256) void k_cpre(const float* __restrict__ Wlr,
                                              const unsigned short* __restrict__ WbT,
                                              unsigned short* __restrict__ Cst) {
  __shared__ unsigned short aF[2048 * 8];
  int blk = blockIdx.x;
  int p = blk >> 2;
  int i0 = (blk & 3) * 64;
  int tid = threadIdx.x;
  const float* Wp = Wlr + (size_t)p * ND * ND;
#pragma unroll
  for (int it = 0; it < 8; ++it) {
    int s = tid + it * 256;
    int kt = s >> 8, r = (s >> 6) & 3, l = s & 63;
    int i = r * 16 + (l & 15);
    int k0 = kt * 32 + (l >> 4) * 8;
    union { uint4 u; unsigned short h[8]; } uu;
#pragma unroll
    for (int j = 0; j < 8; ++j)
      uu.h[j] = f2bf(Wp[(size_t)(k0 + j) * ND + i0 + i]);
    *(uint4*)(aF + (size_t)s * 8) = uu.u;
  }
  __syncthreads();
  int w = tid >> 6, l = tid & 63;
  f32x4 zero = {0.f, 0.f, 0.f, 0.f};
  f32x4 acc[16];
#pragma unroll
  for (int c = 0; c < 16; ++c) acc[c] = zero;
  for (int kt = 0; kt < 8; ++kt) {
    bf16x8 a = *(const bf16x8*)(aF + (size_t)((kt * 4 + w) * 64 + l) * 8);
#pragma unroll
    for (int c = 0; c < 16; ++c) {
      bf16x8 bb = *(const bf16x8*)(WbT + (size_t)((kt * 16 + c) * 64 + l) * 8);
      acc[c] = __builtin_amdgcn_mfma_f32_16x16x32_bf16(a, bb, acc[c], 0, 0, 0);
    }
  }
  unsigned short* Cp = Cst + (size_t)p * ND * ND;
#pragma unroll
  for (int c = 0; c < 16; ++c) {
#pragma unroll
    for (int q = 0; q < 4; ++q) {
      int i = i0 + w * 16 + ((l >> 4) * 4) + q;
      int j = c * 16 + (l & 15);
      int pos = ((i >> 5) * 16 + (j >> 4)) * 512 + (((i >> 3) & 3) * 16 + (j & 15)) * 8 + (i & 7);
      Cp[pos] = f2bf(acc[c][q]);
    }
  }
}

// ---- k_perm: exact order-preserving CSR perm via ballot (no atomics) ----
__global__ __launch_bounds__(64) void k_perm(const void* __restrict__ idxraw,
                                             const int* __restrict__ bases,
                                             int* __restrict__ perm) {
  __shared__ int lflag;
  int l = threadIdx.x;
  int b = blockIdx.x;
  if (l == 0) lflag = 0;
  __syncthreads();
  {
    const unsigned int* w = (const unsigned int*)idxraw;
    unsigned int val = w[((b & 63) * 64 + l) * 2 + 1];
    if (__any(val != 0) && l == 0) atomicOr(&lflag, 1);
  }
  __syncthreads();
  int is32 = lflag;
  int base = b * SB;
  int p = (l < SB) ? load_idx(idxraw, is32, base + l) : 999;
  unsigned long long lt = (l == 63) ? (~0ull >> 1) : ((1ull << l) - 1ull);
  int rank = 0, gq = 0;
#pragma unroll
  for (int q = 0; q < NP; ++q) {
    unsigned long long m = __ballot(p == q);
    if (p == q) { rank = __popcll(m & lt); gq = q; }
  }
  if (l < SB) perm[bases[gq * NSB + b] + rank] = base + l;
}

// ---- k_main v14: R12 body + XCD-clustered (t,p) block mapping. ----
// Within an expert, CSR order == natural edge order, so tile t of expert p
// covers edge window ~[256t, 256t+256) (stride-8 sparse). Mapping
// phys = (t%8) + 8*(8*(t/8) + p) puts all 8 experts' tile-t on the SAME XCD
// (phys % 8 == t % 8 -> same round-robin XCD): the window streams into that
// XCD's L2 once and the 8 tiles consume it densely -> the scattered-row HBM
// wall (~1.1 TB/s, R3-R12) becomes streaming + L2-local permutation.
__global__ __launch_bounds__(512, 8) void k_main(const float* __restrict__ zsrc,
                                                 const float* __restrict__ zdst,
                                                 const int* __restrict__ perm,
                                                 const int* __restrict__ hdr,
                                                 const unsigned short* __restrict__ Cst,
                                                 const float* __restrict__ v,
                                                 const float* __restrict__ bbil,
                                                 float* __restrict__ out) {
  __shared__ unsigned short zs[8192];    // 16 KiB: A-frag layout, granule-XOR
  __shared__ unsigned short zd[8192];    // 16 KiB: row-major 512B/row, XOR
  __shared__ float red[8][TR];
  __shared__ int eids[TR];
  __shared__ int shdr[18];
  int tid = threadIdx.x;
  if (tid < 18) shdr[tid] = hdr[tid];
  __syncthreads();
  // inverse of phys = (t%8) + 8*(8*(t/8) + p)
  int bid = blockIdx.x;
  int g = bid >> 3, r = bid & 7;
  int p = g & 7;
  int t = ((g >> 3) << 3) + r;
  int cnt = shdr[p + 1] - shdr[p];
  if (t * TR >= cnt) return;
  int ebase = shdr[p] + t * TR;
  int nrow = cnt - t * TR; if (nrow > TR) nrow = TR;
  if (tid < TR) eids[tid] = perm[ebase + (tid < nrow ? tid : nrow - 1)];
  __syncthreads();
  int w = tid >> 6, l = tid & 63;
  // ---- staging: wave w stages rows w*4..w*4+3; lane l covers cols [4l,4l+4)
  int kt0 = l >> 3, q0 = (l >> 1) & 3, par0 = l & 1;
#pragma unroll
  for (int i = 0; i < 4; ++i) {
    int row = w * 4 + i;
    int e = eids[row];
    float4 fs = *(const float4*)(zsrc + (size_t)e * ND + l * 4);
    float4 fd = *(const float4*)(zdst + (size_t)e * ND + l * 4);
    union { unsigned long long u; unsigned short h[4]; } us, ud;
    us.h[0] = f2bf(fs.x); us.h[1] = f2bf(fs.y); us.h[2] = f2bf(fs.z); us.h[3] = f2bf(fs.w);
    ud.h[0] = f2bf(fd.x); ud.h[1] = f2bf(fd.y); ud.h[2] = f2bf(fd.z); ud.h[3] = f2bf(fd.w);
    unsigned gg = (unsigned)((kt0 * 2 + (row >> 4)) * 64 + (row & 15) + 16 * q0);
    gg ^= ((gg >> 6) & 7u) << 1;
    *(unsigned long long*)((char*)zs + gg * 16 + par0 * 8) = us.u;
    *(unsigned long long*)((char*)zd + ((unsigned)(row * 512 + l * 8) ^ (((unsigned)row & 7u) << 5))) = ud.u;
  }
  __syncthreads();
  // ---- GEMM: wave w covers col-tiles {2w, 2w+1}; B from L2 ----
  const unsigned short* Cp = Cst + (size_t)p * ND * ND;
  f32x4 zero = {0.f, 0.f, 0.f, 0.f};
  f32x4 acc[2][2];
#pragma unroll
  for (int sr = 0; sr < 2; ++sr)
#pragma unroll
    for (int cl = 0; cl < 2; ++cl) acc[sr][cl] = zero;
  int hh = l >> 4, rr = l & 15;
#pragma unroll
  for (int kt = 0; kt < 8; ++kt) {
    bf16x8 a[2];
#pragma unroll
    for (int sr = 0; sr < 2; ++sr) {
      unsigned gg = (unsigned)((kt * 2 + sr) * 64 + l);
      gg ^= ((gg >> 6) & 7u) << 1;
      a[sr] = *(const bf16x8*)((const char*)zs + gg * 16);
    }
#pragma unroll
    for (int cl = 0; cl < 2; ++cl) {
      bf16x8 bb = *(const bf16x8*)(Cp + (size_t)((kt * 16 + (w * 2 + cl)) * 64 + l) * 8);
#pragma unroll
      for (int sr = 0; sr < 2; ++sr)
        acc[sr][cl] = __builtin_amdgcn_mfma_f32_16x16x32_bf16(a[sr], bb, acc[sr][cl], 0, 0, 0);
    }
  }
  // ---- fused epilogue: bf16 z_dst from LDS; 4-lane-group reduce ----
  float vloc[2];
#pragma unroll
  for (int cl = 0; cl < 2; ++cl)
    vloc[cl] = v[p * ND + (w * 2 + cl) * 16 + rr];
#pragma unroll
  for (int sr = 0; sr < 2; ++sr) {
#pragma unroll
    for (int q = 0; q < 4; ++q) {
      int row = sr * 16 + hh * 4 + q;
      unsigned swz = ((unsigned)row & 7u) << 5;
      float sv = 0.f;
#pragma unroll
      for (int cl = 0; cl < 2; ++cl) {
        int col = (w * 2 + cl) * 16 + rr;
        unsigned byte = ((unsigned)(row * 512 + col * 2)) ^ swz;
        sv = fmaf(acc[sr][cl][q] + vloc[cl], bf2f(*(const unsigned short*)((const char*)zd + byte)), sv);
      }
      sv += __shfl_xor(sv, 1, 64);
      sv += __shfl_xor(sv, 2, 64);
      sv += __shfl_xor(sv, 4, 64);
      sv += __shfl_xor(sv, 8, 64);
      if (rr == 0) red[w][row] = sv;
    }
  }
  __syncthreads();
  if (tid < TR && tid < nrow) {
    float sc = bbil[0];
#pragma unroll
    for (int ww = 0; ww < 8; ++ww) sc += red[ww][tid];
    out[eids[tid]] = sc;
  }
}

extern "C" void kernel_launch(void* const* d_in, const int* in_sizes, int n_in,
                              void* d_out, int out_size, void* d_ws, size_t ws_size,
                              hipStream_t stream) {
  // setup_inputs() dict order: z_src, z_dst, W_lr, b_lr, W_bil, b_bil, lr_pair_idx
  const float* zsrc = (const float*)d_in[0];
  const float* zdst = (const float*)d_in[1];
  const float* Wlr  = (const float*)d_in[2];
  const float* blr  = (const float*)d_in[3];
  const float* Wbil = (const float*)d_in[4];
  const float* bbil = (const float*)d_in[5];
  const void*  idx  = (const void*)d_in[6];
  float* out = (float*)d_out;

  char* ws = (char*)d_ws;
  int* hdr    = (int*)ws;                                  // 72 B
  int* counts = (int*)(ws + 4096);                         // 64 KiB [q][sb]
  int* bases  = (int*)(ws + 73728);                        // 64 KiB [q][sb]
  unsigned short* WbT = (unsigned short*)(ws + 139264);    // 128 KiB
  float* v            = (float*)(ws + 270336);             // 8 KiB
  unsigned short* Cst = (unsigned short*)(ws + 278528);    // 1 MiB
  int* perm           = (int*)(ws + 1327104);              // 256 KiB

  k_pre0<<<296, 256, 0, stream>>>(Wbil, blr, idx, WbT, v, counts);
  k_scan<<<1, 256, 0, stream>>>(counts, hdr, bases);
  k_cpre<<<32, 256, 0, stream>>>(Wlr, WbT, Cst);
  k_perm<<<NSB, 64, 0, stream>>>(idx, bases, perm);
  // grid covers worst-case per-expert tile count (t < 2048): phys < 16384
  k_main<<<16384, 512, 0, stream>>>(zsrc, zdst, perm, hdr, Cst, v, bbil, out);
}